// Round 15
// baseline (26.866 us; speedup 1.0000x reference)
//
#include <hip/hip_runtime.h>
#include <hip/hip_bf16.h>

#define HGT 128
#define WID 128
#define HW  (HGT * WID)          // 16384
#define CCH 64

// fused tiling: 32x4 interior, 34x6 halo (proven best geometry)
#define TILE_W 32
#define TILE_H 4
#define HALO_W 34
#define HALO_H 6
#define NHP    204               // HALO_W * HALO_H
#define NGROUP 13                // ceil(NHP/16)
#define VSLOTS 208               // NGROUP*16

typedef __attribute__((ext_vector_type(8))) short bf16x8;
typedef __attribute__((ext_vector_type(4))) float f32x4;
typedef __attribute__((ext_vector_type(4))) unsigned short u16x4;

// workspace layout (float offsets)
#define BA_OFF   5120            // 48 floats (reduced attn bias) after 20*64*8 ushort frags

__device__ inline short f2bf(float f) {
    unsigned u = __float_as_uint(f);
    unsigned r = (u + 0x7fffu + ((u >> 16) & 1u)) >> 16;   // RNE
    return (short)r;
}
__device__ inline float bf2f(unsigned short u) {
    return __uint_as_float(((unsigned)u) << 16);
}

// ---------------------------------------------------------------------------
// Prep kernel (unchanged — proven correct since R5)
// ---------------------------------------------------------------------------
__global__ void prep_kernel(const float* __restrict__ Wv,
                            const float* __restrict__ Wfg,
                            const float* __restrict__ bfg,
                            const float* __restrict__ Wbg,
                            const float* __restrict__ bbg,
                            float* __restrict__ ws) {
    int idx = blockIdx.x * 256 + threadIdx.x;
    unsigned short* wf = (unsigned short*)ws;
    if (idx < 20 * 64 * 8) {
        int j    = idx & 7;
        int lane = (idx >> 3) & 63;
        int t    = idx >> 9;
        int lo = lane & 15, hi = lane >> 4;
        float val;
        if (t < 8) {
            int nt = t >> 1, kf = t & 1;
            int k = kf * 32 + hi * 8 + j;
            int n = nt * 16 + lo;
            val = Wv[k * 64 + n];
        } else {
            int t2 = t - 8;
            int nt = t2 >> 2, kf = t2 & 3;
            int k = kf * 32 + hi * 8 + j;      // 0..127
            int n = nt * 16 + lo;              // 0..47
            if (n >= 36) {
                val = 0.f;
            } else {
                int h = n / 9, jj = n % 9;
                const float* W = (k < 64) ? Wfg : Wbg;
                int c = (k < 64) ? k : k - 64;
                float s = 0.f;
                #pragma unroll
                for (int i = 0; i < 9; i++) s += W[c * 324 + h * 81 + i * 9 + jj];
                val = s;
            }
        }
        wf[idx] = (unsigned short)f2bf(val);
    } else if (idx < 20 * 64 * 8 + 48) {
        int n = idx - 20 * 64 * 8;
        float s = 0.f;
        if (n < 36) {
            int h = n / 9, jj = n % 9;
            #pragma unroll
            for (int i = 0; i < 9; i++)
                s += bfg[h * 81 + i * 9 + jj] + bbg[h * 81 + i * 9 + jj];
        }
        ws[BA_OFF + n] = s;
    }
}

// ---------------------------------------------------------------------------
// Fused kernel, 32x4 tiles (R13 schedule + bias hoisting):
//   phase1: halo v via MFMA -> v_lds (bf16, XOR-swizzled), 2-deep load pipe;
//           fg/bg group-0 loads pre-issued under the p1 MFMA tail
//   phase2: fg/bg group-1 loads issued first, then a2 frags, then compute
//   barrier; phase3: aggregate -> out.
// Bias vectors loaded ONCE per phase into registers (were re-loaded per
// macro invocation in R13 — ~70 redundant VMEM instrs/thread).
// Grid 512 (2 blocks/CU grid-capped); launch_bounds(256,2).
// ---------------------------------------------------------------------------
__global__ __launch_bounds__(256, 2) void fused_kernel(
        const float* __restrict__ x, const float* __restrict__ fg,
        const float* __restrict__ bg, const float* __restrict__ bv,
        const float* __restrict__ ws, float* __restrict__ out) {
    __shared__ unsigned short v_lds[VSLOTS * 64];          // 26.6 KB
    __shared__ float attn_lds[TILE_W * TILE_H * 37];       // 18.9 KB

    int tid  = threadIdx.x;
    int wave = tid >> 6, lane = tid & 63;
    int lo = lane & 15, hi = lane >> 4;

    // XCD-chunked bijective swizzle (512 = 8 XCDs x 64): vertical-neighbor
    // tiles (halo overlap) land on the same XCD's L2.
    int bid0 = blockIdx.x;
    int bid  = (bid0 & 7) * 64 + (bid0 >> 3);

    int b  = bid >> 7;                 // batch (128 tiles per image)
    int t  = bid & 127;
    int ty = t >> 2, tx = t & 3;       // 32 x 4 tiles of 4x32
    int y0 = ty * TILE_H, x0 = tx * TILE_W;
    const size_t bin = (size_t)b * CCH * HW;
    const unsigned short* wf = (const unsigned short*)ws;

#define LOAD_G(dst, g)                                                        \
    {                                                                         \
        int hp = (g) * 16 + lo;                                               \
        int hps = min(hp, NHP - 1);                                           \
        int rr = hps / HALO_W;                                                \
        int cc = hps - rr * HALO_W;                                           \
        int yy = min(max(y0 - 1 + rr, 0), HGT - 1);                           \
        int xx = min(max(x0 - 1 + cc, 0), WID - 1);                           \
        const float* xp = x + bin + yy * WID + xx;                            \
        _Pragma("unroll")                                                     \
        for (int q = 0; q < 16; q++)                                          \
            dst[q] = xp[(size_t)((q >> 3) * 32 + hi * 8 + (q & 7)) * HW];     \
    }

#define LOAD_P2(frd, grd, ipexpr)                                             \
    {                                                                         \
        int ip = (ipexpr);                                                    \
        int r = ip >> 5, c = ip & 31;                                         \
        const float* fp = fg + bin + (size_t)(y0 + r) * WID + x0 + c;         \
        const float* gp = bg + bin + (size_t)(y0 + r) * WID + x0 + c;         \
        _Pragma("unroll")                                                     \
        for (int q = 0; q < 16; q++)                                          \
            frd[q] = fp[(size_t)((q >> 3) * 32 + hi * 8 + (q & 7)) * HW];     \
        _Pragma("unroll")                                                     \
        for (int q = 0; q < 16; q++)                                          \
            grd[q] = gp[(size_t)((q >> 3) * 32 + hi * 8 + (q & 7)) * HW];     \
    }

    float fr0[16], gr0[16], fr1[16], gr1[16];

    // ================= Phase 1: halo v -> LDS (bf16, swizzled) =============
    {
        bf16x8 a1[8];
        #pragma unroll
        for (int tt = 0; tt < 8; tt++)
            a1[tt] = *(const bf16x8*)(wf + ((size_t)tt * 64 + lane) * 8);

        // hoisted v-bias: one 16B load per nt, reused by every COMP_G
        f32x4 biasv[4];
        #pragma unroll
        for (int nt = 0; nt < 4; nt++)
            biasv[nt] = *(const f32x4*)(bv + nt * 16 + hi * 4);

#define COMP_G(src, g)                                                        \
        {                                                                     \
            int hp = (g) * 16 + lo;                                           \
            bf16x8 bx0, bx1;                                                  \
            _Pragma("unroll")                                                 \
            for (int j = 0; j < 8; j++) {                                     \
                bx0[j] = f2bf(src[j]);                                        \
                bx1[j] = f2bf(src[8 + j]);                                    \
            }                                                                 \
            f32x4 av[4];                                                      \
            _Pragma("unroll")                                                 \
            for (int nt = 0; nt < 4; nt++)                                    \
                av[nt] = biasv[nt];                                           \
            _Pragma("unroll")                                                 \
            for (int nt = 0; nt < 4; nt++) {                                  \
                av[nt] = __builtin_amdgcn_mfma_f32_16x16x32_bf16(a1[nt * 2 + 0], bx0, av[nt], 0, 0, 0); \
                av[nt] = __builtin_amdgcn_mfma_f32_16x16x32_bf16(a1[nt * 2 + 1], bx1, av[nt], 0, 0, 0); \
            }                                                                 \
            char* vb = (char*)v_lds;                                          \
            _Pragma("unroll")                                                 \
            for (int nt = 0; nt < 4; nt++) {                                  \
                u16x4 pk;                                                     \
                _Pragma("unroll")                                             \
                for (int r = 0; r < 4; r++) pk[r] = (unsigned short)f2bf(av[nt][r]); \
                int byte = hp * 128 + ((nt * 32 + hi * 8) ^ ((hp & 7) << 4)); \
                *(u16x4*)(vb + byte) = pk;                                    \
            }                                                                 \
        }

        // groups: wave, 4+wave, 8+wave always valid (<13); 12 only for wave 0
        float xrA[16], xrB[16];
        LOAD_G(xrA, wave)
        LOAD_G(xrB, 4 + wave)
        COMP_G(xrA, wave)
        LOAD_G(xrA, 8 + wave)
        COMP_G(xrB, 4 + wave)
        if (wave == 0) LOAD_G(xrB, 12)
        LOAD_P2(fr0, gr0, wave * 16 + lo)        // pre-issue p2 group 0
        COMP_G(xrA, 8 + wave)
        if (wave == 0) COMP_G(xrB, 12)
    }

    // ================= Phase 2: attn -> LDS (fp32, stride 37) ==============
    {
        LOAD_P2(fr1, gr1, 64 + wave * 16 + lo)   // pre-issue p2 group 1

        bf16x8 a2[12];
        #pragma unroll
        for (int tt = 0; tt < 12; tt++)
            a2[tt] = *(const bf16x8*)(wf + ((size_t)(8 + tt) * 64 + lane) * 8);

        // hoisted attn-bias: one 16B load per nt, reused by both P2_COMPUTEs
        f32x4 biasa[3];
        #pragma unroll
        for (int nt = 0; nt < 3; nt++)
            biasa[nt] = *(const f32x4*)(ws + BA_OFF + nt * 16 + hi * 4);

#define P2_COMPUTE(ipexpr, fr, gr)                                            \
        {                                                                     \
            int ip = (ipexpr);                                                \
            bf16x8 b2_[4];                                                    \
            _Pragma("unroll")                                                 \
            for (int j = 0; j < 8; j++) {                                     \
                b2_[0][j] = f2bf(fr[j]);                                      \
                b2_[1][j] = f2bf(fr[8 + j]);                                  \
                b2_[2][j] = f2bf(gr[j]);                                      \
                b2_[3][j] = f2bf(gr[8 + j]);                                  \
            }                                                                 \
            f32x4 aa[3];                                                      \
            _Pragma("unroll")                                                 \
            for (int nt = 0; nt < 3; nt++)                                    \
                aa[nt] = biasa[nt];                                           \
            _Pragma("unroll")                                                 \
            for (int nt = 0; nt < 3; nt++)                                    \
                _Pragma("unroll")                                             \
                for (int kf = 0; kf < 4; kf++)                                \
                    aa[nt] = __builtin_amdgcn_mfma_f32_16x16x32_bf16(a2[nt * 4 + kf], b2_[kf], aa[nt], 0, 0, 0); \
            float* ab = attn_lds + ip * 37;                                   \
            *(f32x4*)(ab + hi * 4)      = aa[0];                              \
            *(f32x4*)(ab + 16 + hi * 4) = aa[1];                              \
            if (hi == 0) *(f32x4*)(ab + 32) = aa[2];                          \
        }

        P2_COMPUTE(wave * 16 + lo, fr0, gr0)
        P2_COMPUTE(64 + wave * 16 + lo, fr1, gr1)
    }

    __syncthreads();

    // ================= Phase 3: aggregation ================================
    {
        int ip    = tid & 127;
        int hpair = tid >> 7;                 // heads {2*hpair, 2*hpair+1}
        int r = ip >> 5, c = ip & 31;
        int y = y0 + r, xq = x0 + c;

        float acc[32];
        #pragma unroll
        for (int o = 0; o < 32; o++) acc[o] = 0.f;

        const char* vb = (const char*)v_lds;
        const float* ab = attn_lds + ip * 37 + hpair * 18;

        #pragma unroll
        for (int j = 0; j < 9; j++) {
            int dy = j / 3 - 1, dx = j % 3 - 1;
            bool valid = (unsigned)(y + dy) < HGT && (unsigned)(xq + dx) < WID;
            int tp = (r + 1 + dy) * HALO_W + (c + 1 + dx);   // halo slot
            float w0 = valid ? ab[j] : 0.f;
            float w1 = valid ? ab[9 + j] : 0.f;

            int base = tp * 128;
            int sw = (tp & 7) << 4;
            int k0 = hpair * 4;
            bf16x8 ch0 = *(const bf16x8*)(vb + base + (((k0 + 0) * 16) ^ sw));
            bf16x8 ch1 = *(const bf16x8*)(vb + base + (((k0 + 1) * 16) ^ sw));
            bf16x8 ch2 = *(const bf16x8*)(vb + base + (((k0 + 2) * 16) ^ sw));
            bf16x8 ch3 = *(const bf16x8*)(vb + base + (((k0 + 3) * 16) ^ sw));
            #pragma unroll
            for (int e = 0; e < 8; e++) {
                acc[e]      += w0 * bf2f((unsigned short)ch0[e]);
                acc[8 + e]  += w0 * bf2f((unsigned short)ch1[e]);
                acc[16 + e] += w1 * bf2f((unsigned short)ch2[e]);
                acc[24 + e] += w1 * bf2f((unsigned short)ch3[e]);
            }
        }

        float* ob = out + bin + (size_t)(hpair * 32) * HW + (size_t)y * WID + xq;
        #pragma unroll
        for (int o = 0; o < 32; o++)
            ob[(size_t)o * HW] = acc[o];
    }
}

extern "C" void kernel_launch(void* const* d_in, const int* in_sizes, int n_in,
                              void* d_out, int out_size, void* d_ws, size_t ws_size,
                              hipStream_t stream) {
    const float* x   = (const float*)d_in[0];
    const float* fg  = (const float*)d_in[1];
    const float* bg  = (const float*)d_in[2];
    const float* Wv  = (const float*)d_in[3];
    const float* bv  = (const float*)d_in[4];
    const float* Wfg = (const float*)d_in[5];
    const float* bfg = (const float*)d_in[6];
    const float* Wbg = (const float*)d_in[7];
    const float* bbg = (const float*)d_in[8];

    float* ws  = (float*)d_ws;
    float* out = (float*)d_out;

    // 0) pack weight fragments + reduced bias
    prep_kernel<<<41, 256, 0, stream>>>(Wv, Wfg, bfg, Wbg, bbg, ws);

    // 1) fused v + attn + aggregation: 512 blocks (2/CU, grid-capped)
    fused_kernel<<<512, 256, 0, stream>>>(x, fg, bg, bv, ws, out);
}

// Round 16
// 24.807 us; speedup vs baseline: 1.0830x; 1.0830x over previous
//
#include <hip/hip_runtime.h>
#include <hip/hip_bf16.h>

#define HGT 128
#define WID 128
#define HW  (HGT * WID)          // 16384
#define CCH 64

// fused tiling: 32x4 interior, 34x6 halo (proven best geometry)
#define TILE_W 32
#define TILE_H 4
#define HALO_W 34
#define HALO_H 6
#define NHP    204               // HALO_W * HALO_H
#define NGROUP 13                // ceil(NHP/16)
#define VSLOTS 208               // NGROUP*16

typedef __attribute__((ext_vector_type(8))) short bf16x8;
typedef __attribute__((ext_vector_type(4))) float f32x4;
typedef __attribute__((ext_vector_type(4))) unsigned short u16x4;

// workspace layout (float offsets)
#define BA_OFF   5120            // 48 floats (reduced attn bias) after 20*64*8 ushort frags

__device__ inline short f2bf(float f) {
    unsigned u = __float_as_uint(f);
    unsigned r = (u + 0x7fffu + ((u >> 16) & 1u)) >> 16;   // RNE
    return (short)r;
}
__device__ inline float bf2f(unsigned short u) {
    return __uint_as_float(((unsigned)u) << 16);
}

// ---------------------------------------------------------------------------
// Prep kernel (unchanged — proven correct since R5)
// ---------------------------------------------------------------------------
__global__ void prep_kernel(const float* __restrict__ Wv,
                            const float* __restrict__ Wfg,
                            const float* __restrict__ bfg,
                            const float* __restrict__ Wbg,
                            const float* __restrict__ bbg,
                            float* __restrict__ ws) {
    int idx = blockIdx.x * 256 + threadIdx.x;
    unsigned short* wf = (unsigned short*)ws;
    if (idx < 20 * 64 * 8) {
        int j    = idx & 7;
        int lane = (idx >> 3) & 63;
        int t    = idx >> 9;
        int lo = lane & 15, hi = lane >> 4;
        float val;
        if (t < 8) {
            int nt = t >> 1, kf = t & 1;
            int k = kf * 32 + hi * 8 + j;
            int n = nt * 16 + lo;
            val = Wv[k * 64 + n];
        } else {
            int t2 = t - 8;
            int nt = t2 >> 2, kf = t2 & 3;
            int k = kf * 32 + hi * 8 + j;      // 0..127
            int n = nt * 16 + lo;              // 0..47
            if (n >= 36) {
                val = 0.f;
            } else {
                int h = n / 9, jj = n % 9;
                const float* W = (k < 64) ? Wfg : Wbg;
                int c = (k < 64) ? k : k - 64;
                float s = 0.f;
                #pragma unroll
                for (int i = 0; i < 9; i++) s += W[c * 324 + h * 81 + i * 9 + jj];
                val = s;
            }
        }
        wf[idx] = (unsigned short)f2bf(val);
    } else if (idx < 20 * 64 * 8 + 48) {
        int n = idx - 20 * 64 * 8;
        float s = 0.f;
        if (n < 36) {
            int h = n / 9, jj = n % 9;
            #pragma unroll
            for (int i = 0; i < 9; i++)
                s += bfg[h * 81 + i * 9 + jj] + bbg[h * 81 + i * 9 + jj];
        }
        ws[BA_OFF + n] = s;
    }
}

// ---------------------------------------------------------------------------
// Fused kernel, 32x4 tiles (R13 structure + cross-phase load pre-issue):
//   phase1: halo v via MFMA -> v_lds (bf16, XOR-swizzled), 2-deep load pipe;
//           fg/bg group-0 loads pre-issued under the p1 MFMA tail
//   phase2: fg/bg group-1 loads issued first, then a2 frags, then compute
//   barrier; phase3: aggregate -> out.
// Grid 512 (2 blocks/CU grid-capped); launch_bounds(256,2) for reg slack.
// Conversions: manual RNE f2bf everywhere (proven absmax 0.015625).
// ---------------------------------------------------------------------------
__global__ __launch_bounds__(256, 2) void fused_kernel(
        const float* __restrict__ x, const float* __restrict__ fg,
        const float* __restrict__ bg, const float* __restrict__ bv,
        const float* __restrict__ ws, float* __restrict__ out) {
    __shared__ unsigned short v_lds[VSLOTS * 64];          // 26.6 KB
    __shared__ float attn_lds[TILE_W * TILE_H * 37];       // 18.9 KB

    int tid  = threadIdx.x;
    int wave = tid >> 6, lane = tid & 63;
    int lo = lane & 15, hi = lane >> 4;

    // XCD-chunked bijective swizzle (512 = 8 XCDs x 64): vertical-neighbor
    // tiles (halo overlap) land on the same XCD's L2.
    int bid0 = blockIdx.x;
    int bid  = (bid0 & 7) * 64 + (bid0 >> 3);

    int b  = bid >> 7;                 // batch (128 tiles per image)
    int t  = bid & 127;
    int ty = t >> 2, tx = t & 3;       // 32 x 4 tiles of 4x32
    int y0 = ty * TILE_H, x0 = tx * TILE_W;
    const size_t bin = (size_t)b * CCH * HW;
    const unsigned short* wf = (const unsigned short*)ws;

#define LOAD_G(dst, g)                                                        \
    {                                                                         \
        int hp = (g) * 16 + lo;                                               \
        int hps = min(hp, NHP - 1);                                           \
        int rr = hps / HALO_W;                                                \
        int cc = hps - rr * HALO_W;                                           \
        int yy = min(max(y0 - 1 + rr, 0), HGT - 1);                           \
        int xx = min(max(x0 - 1 + cc, 0), WID - 1);                           \
        const float* xp = x + bin + yy * WID + xx;                            \
        _Pragma("unroll")                                                     \
        for (int q = 0; q < 16; q++)                                          \
            dst[q] = xp[(size_t)((q >> 3) * 32 + hi * 8 + (q & 7)) * HW];     \
    }

#define LOAD_P2(frd, grd, ipexpr)                                             \
    {                                                                         \
        int ip = (ipexpr);                                                    \
        int r = ip >> 5, c = ip & 31;                                         \
        const float* fp = fg + bin + (size_t)(y0 + r) * WID + x0 + c;         \
        const float* gp = bg + bin + (size_t)(y0 + r) * WID + x0 + c;         \
        _Pragma("unroll")                                                     \
        for (int q = 0; q < 16; q++)                                          \
            frd[q] = fp[(size_t)((q >> 3) * 32 + hi * 8 + (q & 7)) * HW];     \
        _Pragma("unroll")                                                     \
        for (int q = 0; q < 16; q++)                                          \
            grd[q] = gp[(size_t)((q >> 3) * 32 + hi * 8 + (q & 7)) * HW];     \
    }

    float fr0[16], gr0[16], fr1[16], gr1[16];

    // ================= Phase 1: halo v -> LDS (bf16, swizzled) =============
    {
        bf16x8 a1[8];
        #pragma unroll
        for (int tt = 0; tt < 8; tt++)
            a1[tt] = *(const bf16x8*)(wf + ((size_t)tt * 64 + lane) * 8);

#define COMP_G(src, g)                                                        \
        {                                                                     \
            int hp = (g) * 16 + lo;                                           \
            bf16x8 bx0, bx1;                                                  \
            _Pragma("unroll")                                                 \
            for (int j = 0; j < 8; j++) {                                     \
                bx0[j] = f2bf(src[j]);                                        \
                bx1[j] = f2bf(src[8 + j]);                                    \
            }                                                                 \
            f32x4 av[4];                                                      \
            _Pragma("unroll")                                                 \
            for (int nt = 0; nt < 4; nt++)                                    \
                _Pragma("unroll")                                             \
                for (int r = 0; r < 4; r++)                                   \
                    av[nt][r] = bv[nt * 16 + hi * 4 + r];                     \
            _Pragma("unroll")                                                 \
            for (int nt = 0; nt < 4; nt++) {                                  \
                av[nt] = __builtin_amdgcn_mfma_f32_16x16x32_bf16(a1[nt * 2 + 0], bx0, av[nt], 0, 0, 0); \
                av[nt] = __builtin_amdgcn_mfma_f32_16x16x32_bf16(a1[nt * 2 + 1], bx1, av[nt], 0, 0, 0); \
            }                                                                 \
            char* vb = (char*)v_lds;                                          \
            _Pragma("unroll")                                                 \
            for (int nt = 0; nt < 4; nt++) {                                  \
                u16x4 pk;                                                     \
                _Pragma("unroll")                                             \
                for (int r = 0; r < 4; r++) pk[r] = (unsigned short)f2bf(av[nt][r]); \
                int byte = hp * 128 + ((nt * 32 + hi * 8) ^ ((hp & 7) << 4)); \
                *(u16x4*)(vb + byte) = pk;                                    \
            }                                                                 \
        }

        // groups: wave, 4+wave, 8+wave always valid (<13); 12 only for wave 0
        float xrA[16], xrB[16];
        LOAD_G(xrA, wave)
        LOAD_G(xrB, 4 + wave)
        COMP_G(xrA, wave)
        LOAD_G(xrA, 8 + wave)
        COMP_G(xrB, 4 + wave)
        if (wave == 0) LOAD_G(xrB, 12)
        LOAD_P2(fr0, gr0, wave * 16 + lo)        // pre-issue p2 group 0
        COMP_G(xrA, 8 + wave)
        if (wave == 0) COMP_G(xrB, 12)
    }

    // ================= Phase 2: attn -> LDS (fp32, stride 37) ==============
    {
        LOAD_P2(fr1, gr1, 64 + wave * 16 + lo)   // pre-issue p2 group 1

        bf16x8 a2[12];
        #pragma unroll
        for (int tt = 0; tt < 12; tt++)
            a2[tt] = *(const bf16x8*)(wf + ((size_t)(8 + tt) * 64 + lane) * 8);

#define P2_COMPUTE(ipexpr, fr, gr)                                            \
        {                                                                     \
            int ip = (ipexpr);                                                \
            bf16x8 b2_[4];                                                    \
            _Pragma("unroll")                                                 \
            for (int j = 0; j < 8; j++) {                                     \
                b2_[0][j] = f2bf(fr[j]);                                      \
                b2_[1][j] = f2bf(fr[8 + j]);                                  \
                b2_[2][j] = f2bf(gr[j]);                                      \
                b2_[3][j] = f2bf(gr[8 + j]);                                  \
            }                                                                 \
            f32x4 aa[3];                                                      \
            _Pragma("unroll")                                                 \
            for (int nt = 0; nt < 3; nt++)                                    \
                _Pragma("unroll")                                             \
                for (int r4 = 0; r4 < 4; r4++)                                \
                    aa[nt][r4] = ws[BA_OFF + nt * 16 + hi * 4 + r4];          \
            _Pragma("unroll")                                                 \
            for (int nt = 0; nt < 3; nt++)                                    \
                _Pragma("unroll")                                             \
                for (int kf = 0; kf < 4; kf++)                                \
                    aa[nt] = __builtin_amdgcn_mfma_f32_16x16x32_bf16(a2[nt * 4 + kf], b2_[kf], aa[nt], 0, 0, 0); \
            float* ab = attn_lds + ip * 37;                                   \
            *(f32x4*)(ab + hi * 4)      = aa[0];                              \
            *(f32x4*)(ab + 16 + hi * 4) = aa[1];                              \
            if (hi == 0) *(f32x4*)(ab + 32) = aa[2];                          \
        }

        P2_COMPUTE(wave * 16 + lo, fr0, gr0)
        P2_COMPUTE(64 + wave * 16 + lo, fr1, gr1)
    }

    __syncthreads();

    // ================= Phase 3: aggregation ================================
    {
        int ip    = tid & 127;
        int hpair = tid >> 7;                 // heads {2*hpair, 2*hpair+1}
        int r = ip >> 5, c = ip & 31;
        int y = y0 + r, xq = x0 + c;

        float acc[32];
        #pragma unroll
        for (int o = 0; o < 32; o++) acc[o] = 0.f;

        const char* vb = (const char*)v_lds;
        const float* ab = attn_lds + ip * 37 + hpair * 18;

        #pragma unroll
        for (int j = 0; j < 9; j++) {
            int dy = j / 3 - 1, dx = j % 3 - 1;
            bool valid = (unsigned)(y + dy) < HGT && (unsigned)(xq + dx) < WID;
            int tp = (r + 1 + dy) * HALO_W + (c + 1 + dx);   // halo slot
            float w0 = valid ? ab[j] : 0.f;
            float w1 = valid ? ab[9 + j] : 0.f;

            int base = tp * 128;
            int sw = (tp & 7) << 4;
            int k0 = hpair * 4;
            bf16x8 ch0 = *(const bf16x8*)(vb + base + (((k0 + 0) * 16) ^ sw));
            bf16x8 ch1 = *(const bf16x8*)(vb + base + (((k0 + 1) * 16) ^ sw));
            bf16x8 ch2 = *(const bf16x8*)(vb + base + (((k0 + 2) * 16) ^ sw));
            bf16x8 ch3 = *(const bf16x8*)(vb + base + (((k0 + 3) * 16) ^ sw));
            #pragma unroll
            for (int e = 0; e < 8; e++) {
                acc[e]      += w0 * bf2f((unsigned short)ch0[e]);
                acc[8 + e]  += w0 * bf2f((unsigned short)ch1[e]);
                acc[16 + e] += w1 * bf2f((unsigned short)ch2[e]);
                acc[24 + e] += w1 * bf2f((unsigned short)ch3[e]);
            }
        }

        float* ob = out + bin + (size_t)(hpair * 32) * HW + (size_t)y * WID + xq;
        #pragma unroll
        for (int o = 0; o < 32; o++)
            ob[(size_t)o * HW] = acc[o];
    }
}

extern "C" void kernel_launch(void* const* d_in, const int* in_sizes, int n_in,
                              void* d_out, int out_size, void* d_ws, size_t ws_size,
                              hipStream_t stream) {
    const float* x   = (const float*)d_in[0];
    const float* fg  = (const float*)d_in[1];
    const float* bg  = (const float*)d_in[2];
    const float* Wv  = (const float*)d_in[3];
    const float* bv  = (const float*)d_in[4];
    const float* Wfg = (const float*)d_in[5];
    const float* bfg = (const float*)d_in[6];
    const float* Wbg = (const float*)d_in[7];
    const float* bbg = (const float*)d_in[8];

    float* ws  = (float*)d_ws;
    float* out = (float*)d_out;

    // 0) pack weight fragments + reduced bias
    prep_kernel<<<41, 256, 0, stream>>>(Wv, Wfg, bfg, Wbg, bbg, ws);

    // 1) fused v + attn + aggregation: 512 blocks (2/CU, grid-capped)
    fused_kernel<<<512, 256, 0, stream>>>(x, fg, bg, bv, ws, out);
}